// Round 4
// baseline (3371.051 us; speedup 1.0000x reference)
//
#include <hip/hip_runtime.h>
#include <hip/hip_bf16.h>

// RNN-T Joiner. N=8 T=512 U=64 J=512 V=500 (padded to 512).
// ws: enc_p f32 [4096,512] (8MB) | dec_p f32 [512,512] (1MB) | wimg bf16 swizzled [16kt][32KB]
// joiner: BM=128 (2t x 64u), BN=512 (all V), BK=32, 8 waves (2x4), wave tile 64x128.
// LDS 40KB -> 4 blocks/CU.  Epilogue: 8 octants of 16 rows through LDS -> coalesced streams.

typedef __attribute__((ext_vector_type(4))) float f32x4;
typedef __attribute__((ext_vector_type(8))) short s16x8;

static __device__ __forceinline__ unsigned short f2bf(float x) {
    union { float f; unsigned u; } v; v.f = x;
    return (unsigned short)((v.u + 0x7FFFu + ((v.u >> 16) & 1u)) >> 16);  // RNE
}

static __device__ __forceinline__ float fast_tanh(float x) {
    float e = __expf(2.0f * x);
    float r = __builtin_amdgcn_rcpf(e + 1.0f);
    return __builtin_fmaf(-2.0f, r, 1.0f);
}

#define GLOAD16(gsrc, ldst)                                                  \
    __builtin_amdgcn_global_load_lds(                                        \
        (const __attribute__((address_space(1))) unsigned int*)(gsrc),       \
        (__attribute__((address_space(3))) unsigned int*)(ldst), 16, 0, 0)

// 64B-row swizzle: row r, 16B-slot c (c = k8 chunk, k = c*8..c*8+7)
// byte = r*64 + ((c ^ ((r>>1)&3)) << 4)   -> 2-way max on b128 access = free
static __device__ __forceinline__ unsigned swz64(int r, int c) {
    return (unsigned)(r * 64 + ((c ^ ((r >> 1) & 3)) << 4));
}

// ---------------- projection GEMM (unchanged, verified) ----------------
__global__ __launch_bounds__(256) void proj_gemm(
    const float* __restrict__ A, const float* __restrict__ W,
    const float* __restrict__ b, float* __restrict__ C)
{
    __shared__ unsigned short As[128 * 64];
    __shared__ unsigned short Bs[128 * 64];
    const int mt = blockIdx.x, jt = blockIdx.y;
    const int tid = threadIdx.x;
    const int lane = tid & 63, wid = tid >> 6;
    const int wm = wid >> 1, wn = wid & 1;

    f32x4 acc[4][4];
    const f32x4 zero = {0.f, 0.f, 0.f, 0.f};
    #pragma unroll
    for (int i = 0; i < 4; ++i)
        #pragma unroll
        for (int j = 0; j < 4; ++j) acc[i][j] = zero;

    const int c8 = (tid & 7) * 8;
    const int rbase = tid >> 3;

    for (int kt = 0; kt < 8; ++kt) {
        __syncthreads();
        #pragma unroll
        for (int p = 0; p < 4; ++p) {
            int r = p * 32 + rbase;
            int byte = (r * 128 + c8 * 2) ^ ((r & 7) << 4);
            {
                const float* s = A + (size_t)(mt * 128 + r) * 512 + kt * 64 + c8;
                f32x4 v0 = *(const f32x4*)s, v1 = *(const f32x4*)(s + 4);
                s16x8 pk;
                pk[0] = (short)f2bf(v0[0]); pk[1] = (short)f2bf(v0[1]);
                pk[2] = (short)f2bf(v0[2]); pk[3] = (short)f2bf(v0[3]);
                pk[4] = (short)f2bf(v1[0]); pk[5] = (short)f2bf(v1[1]);
                pk[6] = (short)f2bf(v1[2]); pk[7] = (short)f2bf(v1[3]);
                *(s16x8*)((char*)As + byte) = pk;
            }
            {
                const float* s = W + (size_t)(jt * 128 + r) * 512 + kt * 64 + c8;
                f32x4 v0 = *(const f32x4*)s, v1 = *(const f32x4*)(s + 4);
                s16x8 pk;
                pk[0] = (short)f2bf(v0[0]); pk[1] = (short)f2bf(v0[1]);
                pk[2] = (short)f2bf(v0[2]); pk[3] = (short)f2bf(v0[3]);
                pk[4] = (short)f2bf(v1[0]); pk[5] = (short)f2bf(v1[1]);
                pk[6] = (short)f2bf(v1[2]); pk[7] = (short)f2bf(v1[3]);
                *(s16x8*)((char*)Bs + byte) = pk;
            }
        }
        __syncthreads();
        #pragma unroll
        for (int kk = 0; kk < 2; ++kk) {
            s16x8 af[4], bfr[4];
            #pragma unroll
            for (int mi = 0; mi < 4; ++mi) {
                int row = wm * 64 + mi * 16 + (lane & 15);
                int byte = (row * 128 + kk * 64 + ((lane >> 4) * 16)) ^ ((row & 7) << 4);
                af[mi] = *(const s16x8*)((const char*)As + byte);
            }
            #pragma unroll
            for (int ni = 0; ni < 4; ++ni) {
                int row = wn * 64 + ni * 16 + (lane & 15);
                int byte = (row * 128 + kk * 64 + ((lane >> 4) * 16)) ^ ((row & 7) << 4);
                bfr[ni] = *(const s16x8*)((const char*)Bs + byte);
            }
            #pragma unroll
            for (int mi = 0; mi < 4; ++mi)
                #pragma unroll
                for (int ni = 0; ni < 4; ++ni)
                    acc[mi][ni] = __builtin_amdgcn_mfma_f32_16x16x32_bf16(
                        af[mi], bfr[ni], acc[mi][ni], 0, 0, 0);
        }
    }

    #pragma unroll
    for (int ni = 0; ni < 4; ++ni) {
        int col = jt * 128 + wn * 64 + ni * 16 + (lane & 15);
        float bias = b[col];
        #pragma unroll
        for (int mi = 0; mi < 4; ++mi) {
            int row0 = mt * 128 + wm * 64 + mi * 16 + ((lane >> 4) << 2);
            #pragma unroll
            for (int j = 0; j < 4; ++j)
                C[(size_t)(row0 + j) * 512 + col] = acc[mi][ni][j] + bias;
        }
    }
}

// ---------------- W_out -> bf16, pre-swizzled image [16 kt][32 KB] ----------------
__global__ __launch_bounds__(256) void conv_wout(
    const float* __restrict__ W, unsigned short* __restrict__ img)
{
    int tid = blockIdx.x * 256 + threadIdx.x;   // 32768: kt(16) x v(512) x chunk(4)
    int cc = tid & 3, v = (tid >> 2) & 511, kt = tid >> 11;
    s16x8 pk = {0, 0, 0, 0, 0, 0, 0, 0};
    if (v < 500) {
        const float* s = W + (size_t)v * 512 + kt * 32 + cc * 8;
        f32x4 a = *(const f32x4*)s, b = *(const f32x4*)(s + 4);
        pk[0] = (short)f2bf(a[0]); pk[1] = (short)f2bf(a[1]);
        pk[2] = (short)f2bf(a[2]); pk[3] = (short)f2bf(a[3]);
        pk[4] = (short)f2bf(b[0]); pk[5] = (short)f2bf(b[1]);
        pk[6] = (short)f2bf(b[2]); pk[7] = (short)f2bf(b[3]);
    }
    unsigned byte = swz64(v, cc);
    *(s16x8*)((char*)img + (size_t)kt * 32768 + byte) = pk;
}

// ---------------- fused tanh + vocab GEMM ----------------
__global__ __launch_bounds__(512, 8) void joiner_main(
    const float* __restrict__ enc, const float* __restrict__ dec,
    const unsigned short* __restrict__ Wimg, const float* __restrict__ bout,
    float* __restrict__ out)
{
    __shared__ __align__(16) char raw[40960];            // 40 KB -> 4 blocks/CU
    unsigned short* As = (unsigned short*)raw;           // 8 KB  [128 rows][32 k]
    unsigned short* Bs = (unsigned short*)(raw + 8192);  // 32 KB [512 v][32 k]
    float* ep = (float*)raw;                             // epilogue [16][516] f32 = 33 KB

    const int bid = blockIdx.x;
    const int mt = bid & 255, n = bid >> 8;
    const int tid = threadIdx.x, lane = tid & 63, wid = tid >> 6;
    const int wm = wid >> 2, wn = wid & 3;     // 2 x 4 waves

    const float* encN = enc + (size_t)n * (512 * 512);
    const float* decN = dec + (size_t)n * (64 * 512);

    f32x4 acc[4][8];
    const f32x4 zero = {0.f, 0.f, 0.f, 0.f};
    #pragma unroll
    for (int i = 0; i < 4; ++i)
        #pragma unroll
        for (int j = 0; j < 8; ++j) acc[i][j] = zero;

    // A staging: thread -> row r = tid>>2 (0..127), 16B chunk c16 = tid&3 (k = c16*8..+7)
    const int r = tid >> 2;
    const int c16 = tid & 3;
    const int tt = r >> 6, u = r & 63;
    const float* erow = encN + (size_t)(mt * 2 + tt) * 512 + c16 * 8;
    const float* drow = decN + (size_t)u * 512 + c16 * 8;
    const unsigned abyte = swz64(r, c16);
    // B staging: wave wid copies 4KB in 4 x 1KB gload_lds
    const char* bsrc0 = (const char*)Wimg + (size_t)wid * 4096 + (size_t)lane * 16;
    char* bdst0 = (char*)Bs + wid * 4096;

    // prefetched A operands for current kt
    f32x4 ee0, ee1, dd0, dd1;
    ee0 = *(const f32x4*)erow;        ee1 = *(const f32x4*)(erow + 4);
    dd0 = *(const f32x4*)drow;        dd1 = *(const f32x4*)(drow + 4);

    for (int kt = 0; kt < 16; ++kt) {
        __syncthreads();
        // ---- stage A: tanh(enc+dec) -> bf16, swizzled 16B ds_write ----
        {
            s16x8 p;
            p[0] = (short)f2bf(fast_tanh(ee0[0] + dd0[0]));
            p[1] = (short)f2bf(fast_tanh(ee0[1] + dd0[1]));
            p[2] = (short)f2bf(fast_tanh(ee0[2] + dd0[2]));
            p[3] = (short)f2bf(fast_tanh(ee0[3] + dd0[3]));
            p[4] = (short)f2bf(fast_tanh(ee1[0] + dd1[0]));
            p[5] = (short)f2bf(fast_tanh(ee1[1] + dd1[1]));
            p[6] = (short)f2bf(fast_tanh(ee1[2] + dd1[2]));
            p[7] = (short)f2bf(fast_tanh(ee1[3] + dd1[3]));
            *(s16x8*)((char*)As + abyte) = p;
        }
        // ---- stage B: async copy of pre-swizzled image slice (no VALU) ----
        {
            const char* g = bsrc0 + (size_t)kt * 32768;
            #pragma unroll
            for (int i = 0; i < 4; ++i)
                GLOAD16(g + i * 1024, bdst0 + i * 1024);
        }
        // ---- prefetch A for kt+1 (drains with B at the barrier) ----
        if (kt < 15) {
            const float* e_ = erow + (kt + 1) * 32;
            const float* d_ = drow + (kt + 1) * 32;
            ee0 = *(const f32x4*)e_;   ee1 = *(const f32x4*)(e_ + 4);
            dd0 = *(const f32x4*)d_;   dd1 = *(const f32x4*)(d_ + 4);
        }
        __syncthreads();
        // ---- MFMA: K=32 in one shot; operands swapped (v-major C) ----
        {
            s16x8 af[4], bfr[8];
            const int c = lane >> 4, lr = lane & 15;
            #pragma unroll
            for (int mi = 0; mi < 4; ++mi) {
                int row = wm * 64 + mi * 16 + lr;
                af[mi] = *(const s16x8*)((const char*)As + swz64(row, c));
            }
            #pragma unroll
            for (int ni = 0; ni < 8; ++ni) {
                int row = wn * 128 + ni * 16 + lr;
                bfr[ni] = *(const s16x8*)((const char*)Bs + swz64(row, c));
            }
            #pragma unroll
            for (int mi = 0; mi < 4; ++mi)
                #pragma unroll
                for (int ni = 0; ni < 8; ++ni)
                    acc[mi][ni] = __builtin_amdgcn_mfma_f32_16x16x32_bf16(
                        bfr[ni], af[mi], acc[mi][ni], 0, 0, 0);
        }
    }

    // ---- epilogue: 8 octants of 16 rows; LDS transpose -> contiguous streams ----
    // acc[mi][ni][j]: m = wm*64+mi*16+(lane&15), v = wn*128+ni*16+(lane>>4)*4+j
    const int g4 = (lane >> 4) << 2, c = lane & 15;
    const size_t slab = ((size_t)n * 32768 + (size_t)mt * 128) * 500;
    #pragma unroll
    for (int o = 0; o < 8; ++o) {
        __syncthreads();   // previous LDS users done
        if (wm == (o >> 2)) {
            const int mi = o & 3;
            #pragma unroll
            for (int ni = 0; ni < 8; ++ni) {
                int v4 = wn * 128 + ni * 16 + g4;
                if (v4 < 500) {
                    f32x4 bias = *(const f32x4*)(bout + v4);
                    f32x4 ov;
                    ov[0] = acc[mi][ni][0] + bias[0];
                    ov[1] = acc[mi][ni][1] + bias[1];
                    ov[2] = acc[mi][ni][2] + bias[2];
                    ov[3] = acc[mi][ni][3] + bias[3];
                    *(f32x4*)(ep + c * 516 + v4) = ov;
                }
            }
        }
        __syncthreads();
        const size_t obase = slab + (size_t)o * (16 * 500);
        #pragma unroll
        for (int i = 0; i < 4; ++i) {
            int idx = i * 512 + tid;                    // f32x4 chunk id, 2000 total
            if (idx < 2000) {
                int rr = idx / 125;                     // 125 chunks per 500-f32 row
                int vi = (idx - rr * 125) * 4;
                f32x4 ov = *(const f32x4*)(ep + rr * 516 + vi);
                __builtin_nontemporal_store(ov, (f32x4*)(out + obase + (size_t)idx * 4));
            }
        }
    }
}

extern "C" void kernel_launch(void* const* d_in, const int* in_sizes, int n_in,
                              void* d_out, int out_size, void* d_ws, size_t ws_size,
                              hipStream_t stream) {
    const float* encoder_out = (const float*)d_in[0];  // [8,512,512]
    const float* decoder_out = (const float*)d_in[1];  // [8,64,512]
    const float* W_enc = (const float*)d_in[2];
    const float* b_enc = (const float*)d_in[3];
    const float* W_dec = (const float*)d_in[4];
    const float* b_dec = (const float*)d_in[5];
    const float* W_out = (const float*)d_in[6];        // [500,512]
    const float* b_out = (const float*)d_in[7];        // [500]
    float* out = (float*)d_out;                        // [8,512,64,500]

    float* enc_p = (float*)d_ws;                                   // 8 MB
    float* dec_p = enc_p + (size_t)8 * 512 * 512;                  // 1 MB
    unsigned short* wimg = (unsigned short*)(dec_p + (size_t)8 * 64 * 512);  // 512 KB

    conv_wout<<<dim3(128), 256, 0, stream>>>(W_out, wimg);
    proj_gemm<<<dim3(32, 4), 256, 0, stream>>>(encoder_out, W_enc, b_enc, enc_p);
    proj_gemm<<<dim3(4, 4), 256, 0, stream>>>(decoder_out, W_dec, b_dec, dec_p);
    joiner_main<<<dim3(2048), 512, 0, stream>>>(enc_p, dec_p, wimg, b_out, out);
}

// Round 5
// 269.895 us; speedup vs baseline: 12.4902x; 12.4902x over previous
//
#include <hip/hip_runtime.h>
#include <hip/hip_bf16.h>

// RNN-T Joiner. N=8 T=512 U=64 J=512 V=500 (padded to 512).
// ws: enc_p f32 [4096,512] (8MB) | dec_p f32 [512,512] (1MB) | wimg bf16 swizzled [16kt][32KB]
// joiner: BM=64 (1 t x 64 u), BN=512 (all V), BK=32, 4 waves (1x4), wave tile 64x128.
// Double-buffered LDS (72 KB -> 2 blocks/CU), single barrier per k-step (2-phase).
// acc footprint 128 regs -> launch_bounds(256,2) (R4 lesson: never cap below acc size).

typedef __attribute__((ext_vector_type(4))) float f32x4;
typedef __attribute__((ext_vector_type(8))) short s16x8;

static __device__ __forceinline__ unsigned short f2bf(float x) {
    union { float f; unsigned u; } v; v.f = x;
    return (unsigned short)((v.u + 0x7FFFu + ((v.u >> 16) & 1u)) >> 16);  // RNE
}

static __device__ __forceinline__ float fast_tanh(float x) {
    float e = __expf(2.0f * x);
    float r = __builtin_amdgcn_rcpf(e + 1.0f);
    return __builtin_fmaf(-2.0f, r, 1.0f);
}

#define GLOAD16(gsrc, ldst)                                                  \
    __builtin_amdgcn_global_load_lds(                                        \
        (const __attribute__((address_space(1))) unsigned int*)(gsrc),       \
        (__attribute__((address_space(3))) unsigned int*)(ldst), 16, 0, 0)

// 64B-row swizzle: row r, 16B-slot c; byte = r*64 + ((c ^ ((r>>1)&3)) << 4)
static __device__ __forceinline__ unsigned swz64(int r, int c) {
    return (unsigned)(r * 64 + ((c ^ ((r >> 1) & 3)) << 4));
}

// ---------------- projection GEMM (unchanged, verified) ----------------
__global__ __launch_bounds__(256) void proj_gemm(
    const float* __restrict__ A, const float* __restrict__ W,
    const float* __restrict__ b, float* __restrict__ C)
{
    __shared__ unsigned short As[128 * 64];
    __shared__ unsigned short Bs[128 * 64];
    const int mt = blockIdx.x, jt = blockIdx.y;
    const int tid = threadIdx.x;
    const int lane = tid & 63, wid = tid >> 6;
    const int wm = wid >> 1, wn = wid & 1;

    f32x4 acc[4][4];
    const f32x4 zero = {0.f, 0.f, 0.f, 0.f};
    #pragma unroll
    for (int i = 0; i < 4; ++i)
        #pragma unroll
        for (int j = 0; j < 4; ++j) acc[i][j] = zero;

    const int c8 = (tid & 7) * 8;
    const int rbase = tid >> 3;

    for (int kt = 0; kt < 8; ++kt) {
        __syncthreads();
        #pragma unroll
        for (int p = 0; p < 4; ++p) {
            int r = p * 32 + rbase;
            int byte = (r * 128 + c8 * 2) ^ ((r & 7) << 4);
            {
                const float* s = A + (size_t)(mt * 128 + r) * 512 + kt * 64 + c8;
                f32x4 v0 = *(const f32x4*)s, v1 = *(const f32x4*)(s + 4);
                s16x8 pk;
                pk[0] = (short)f2bf(v0[0]); pk[1] = (short)f2bf(v0[1]);
                pk[2] = (short)f2bf(v0[2]); pk[3] = (short)f2bf(v0[3]);
                pk[4] = (short)f2bf(v1[0]); pk[5] = (short)f2bf(v1[1]);
                pk[6] = (short)f2bf(v1[2]); pk[7] = (short)f2bf(v1[3]);
                *(s16x8*)((char*)As + byte) = pk;
            }
            {
                const float* s = W + (size_t)(jt * 128 + r) * 512 + kt * 64 + c8;
                f32x4 v0 = *(const f32x4*)s, v1 = *(const f32x4*)(s + 4);
                s16x8 pk;
                pk[0] = (short)f2bf(v0[0]); pk[1] = (short)f2bf(v0[1]);
                pk[2] = (short)f2bf(v0[2]); pk[3] = (short)f2bf(v0[3]);
                pk[4] = (short)f2bf(v1[0]); pk[5] = (short)f2bf(v1[1]);
                pk[6] = (short)f2bf(v1[2]); pk[7] = (short)f2bf(v1[3]);
                *(s16x8*)((char*)Bs + byte) = pk;
            }
        }
        __syncthreads();
        #pragma unroll
        for (int kk = 0; kk < 2; ++kk) {
            s16x8 af[4], bfr[4];
            #pragma unroll
            for (int mi = 0; mi < 4; ++mi) {
                int row = wm * 64 + mi * 16 + (lane & 15);
                int byte = (row * 128 + kk * 64 + ((lane >> 4) * 16)) ^ ((row & 7) << 4);
                af[mi] = *(const s16x8*)((const char*)As + byte);
            }
            #pragma unroll
            for (int ni = 0; ni < 4; ++ni) {
                int row = wn * 64 + ni * 16 + (lane & 15);
                int byte = (row * 128 + kk * 64 + ((lane >> 4) * 16)) ^ ((row & 7) << 4);
                bfr[ni] = *(const s16x8*)((const char*)Bs + byte);
            }
            #pragma unroll
            for (int mi = 0; mi < 4; ++mi)
                #pragma unroll
                for (int ni = 0; ni < 4; ++ni)
                    acc[mi][ni] = __builtin_amdgcn_mfma_f32_16x16x32_bf16(
                        af[mi], bfr[ni], acc[mi][ni], 0, 0, 0);
        }
    }

    #pragma unroll
    for (int ni = 0; ni < 4; ++ni) {
        int col = jt * 128 + wn * 64 + ni * 16 + (lane & 15);
        float bias = b[col];
        #pragma unroll
        for (int mi = 0; mi < 4; ++mi) {
            int row0 = mt * 128 + wm * 64 + mi * 16 + ((lane >> 4) << 2);
            #pragma unroll
            for (int j = 0; j < 4; ++j)
                C[(size_t)(row0 + j) * 512 + col] = acc[mi][ni][j] + bias;
        }
    }
}

// ---------------- W_out -> bf16, pre-swizzled image [16 kt][32 KB] ----------------
__global__ __launch_bounds__(256) void conv_wout(
    const float* __restrict__ W, unsigned short* __restrict__ img)
{
    int tid = blockIdx.x * 256 + threadIdx.x;   // 32768: kt(16) x v(512) x chunk(4)
    int cc = tid & 3, v = (tid >> 2) & 511, kt = tid >> 11;
    s16x8 pk = {0, 0, 0, 0, 0, 0, 0, 0};
    if (v < 500) {
        const float* s = W + (size_t)v * 512 + kt * 32 + cc * 8;
        f32x4 a = *(const f32x4*)s, b = *(const f32x4*)(s + 4);
        pk[0] = (short)f2bf(a[0]); pk[1] = (short)f2bf(a[1]);
        pk[2] = (short)f2bf(a[2]); pk[3] = (short)f2bf(a[3]);
        pk[4] = (short)f2bf(b[0]); pk[5] = (short)f2bf(b[1]);
        pk[6] = (short)f2bf(b[2]); pk[7] = (short)f2bf(b[3]);
    }
    unsigned byte = swz64(v, cc);
    *(s16x8*)((char*)img + (size_t)kt * 32768 + byte) = pk;
}

// ---------------- fused tanh + vocab GEMM ----------------
__global__ __launch_bounds__(256, 2) void joiner_main(
    const float* __restrict__ enc, const float* __restrict__ dec,
    const unsigned short* __restrict__ Wimg, const float* __restrict__ bout,
    float* __restrict__ out)
{
    __shared__ __align__(16) char raw[73728];             // 72 KB -> 2 blocks/CU
    unsigned short* As0 = (unsigned short*)raw;           // 4 KB [64 rows][32 k]
    unsigned short* As1 = (unsigned short*)(raw + 4096);  // 4 KB
    unsigned short* Bs0 = (unsigned short*)(raw + 8192);  // 32 KB [512 v][32 k]
    unsigned short* Bs1 = (unsigned short*)(raw + 40960); // 32 KB
    float* ep = (float*)raw;                              // epilogue [16][516] f32 = 33 KB

    const int bid = blockIdx.x;
    const int mt = bid & 511, n = bid >> 9;    // t = mt, rows = 64 u values
    const int tid = threadIdx.x, lane = tid & 63, wid = tid >> 6;
    const int wn = wid;                        // 4 waves across V

    const float* encN = enc + (size_t)n * (512 * 512);
    const float* decN = dec + (size_t)n * (64 * 512);

    f32x4 acc[4][8];
    const f32x4 zero = {0.f, 0.f, 0.f, 0.f};
    #pragma unroll
    for (int i = 0; i < 4; ++i)
        #pragma unroll
        for (int j = 0; j < 8; ++j) acc[i][j] = zero;

    // A staging: thread -> row r = tid>>2 (0..63 = u), 16B chunk c16 = tid&3
    const int r = tid >> 2;
    const int c16 = tid & 3;
    const float* erow = encN + (size_t)mt * 512 + c16 * 8;   // t == mt
    const float* drow = decN + (size_t)r * 512 + c16 * 8;    // u == r
    const unsigned abyte = swz64(r, c16);
    // B staging: wave wid copies 8KB in 8 x 1KB gload_lds (dest wave-uniform base)
    const char* bsrc0 = (const char*)Wimg + (size_t)wid * 8192 + (size_t)lane * 16;
    const int bdoff = wid * 8192;

    f32x4 ee0, ee1, dd0, dd1;

    // ---- prologue: stage kt=0 into buf0, prefetch regs for kt=1 ----
    ee0 = *(const f32x4*)erow;       ee1 = *(const f32x4*)(erow + 4);
    dd0 = *(const f32x4*)drow;       dd1 = *(const f32x4*)(drow + 4);
    {
        s16x8 p;
        p[0] = (short)f2bf(fast_tanh(ee0[0] + dd0[0]));
        p[1] = (short)f2bf(fast_tanh(ee0[1] + dd0[1]));
        p[2] = (short)f2bf(fast_tanh(ee0[2] + dd0[2]));
        p[3] = (short)f2bf(fast_tanh(ee0[3] + dd0[3]));
        p[4] = (short)f2bf(fast_tanh(ee1[0] + dd1[0]));
        p[5] = (short)f2bf(fast_tanh(ee1[1] + dd1[1]));
        p[6] = (short)f2bf(fast_tanh(ee1[2] + dd1[2]));
        p[7] = (short)f2bf(fast_tanh(ee1[3] + dd1[3]));
        *(s16x8*)((char*)As0 + abyte) = p;
        #pragma unroll
        for (int i = 0; i < 8; ++i)
            GLOAD16(bsrc0 + i * 1024, (char*)Bs0 + bdoff + i * 1024);
        ee0 = *(const f32x4*)(erow + 32);  ee1 = *(const f32x4*)(erow + 36);
        dd0 = *(const f32x4*)(drow + 32);  dd1 = *(const f32x4*)(drow + 36);
    }
    __syncthreads();

    // ---- main loop: single barrier per k-step, double-buffered ----
    #pragma unroll
    for (int kt = 0; kt < 16; ++kt) {
        const char* Ac = (char*)((kt & 1) ? As1 : As0);
        const char* Bc = (char*)((kt & 1) ? Bs1 : Bs0);
        char* An = (char*)((kt & 1) ? As0 : As1);
        char* Bn = (char*)((kt & 1) ? Bs0 : Bs1);

        // 1. fragment reads for current tile
        s16x8 af[4], bfr[8];
        const int cc = lane >> 4, lr = lane & 15;
        #pragma unroll
        for (int mi = 0; mi < 4; ++mi)
            af[mi] = *(const s16x8*)(Ac + swz64(mi * 16 + lr, cc));
        #pragma unroll
        for (int ni = 0; ni < 8; ++ni)
            bfr[ni] = *(const s16x8*)(Bc + swz64(wn * 128 + ni * 16 + lr, cc));

        // 2. stage next A (tanh VALU overlaps MFMA pipe)
        if (kt < 15) {
            s16x8 p;
            p[0] = (short)f2bf(fast_tanh(ee0[0] + dd0[0]));
            p[1] = (short)f2bf(fast_tanh(ee0[1] + dd0[1]));
            p[2] = (short)f2bf(fast_tanh(ee0[2] + dd0[2]));
            p[3] = (short)f2bf(fast_tanh(ee0[3] + dd0[3]));
            p[4] = (short)f2bf(fast_tanh(ee1[0] + dd1[0]));
            p[5] = (short)f2bf(fast_tanh(ee1[1] + dd1[1]));
            p[6] = (short)f2bf(fast_tanh(ee1[2] + dd1[2]));
            p[7] = (short)f2bf(fast_tanh(ee1[3] + dd1[3]));
            *(s16x8*)(An + abyte) = p;
            // 3. stage next B (async, drains at the barrier)
            const char* g = bsrc0 + (size_t)(kt + 1) * 32768;
            #pragma unroll
            for (int i = 0; i < 8; ++i)
                GLOAD16(g + i * 1024, Bn + bdoff + i * 1024);
        }
        // 4. register prefetch for kt+2 (WAR on ee/dd limits hoisting to 1 iter)
        if (kt < 14) {
            const float* e_ = erow + (kt + 2) * 32;
            const float* d_ = drow + (kt + 2) * 32;
            ee0 = *(const f32x4*)e_;   ee1 = *(const f32x4*)(e_ + 4);
            dd0 = *(const f32x4*)d_;   dd1 = *(const f32x4*)(d_ + 4);
        }
        // 5. MFMA (swapped operands: C lane holds m=lane&15, v4=(lane>>4)*4)
        #pragma unroll
        for (int mi = 0; mi < 4; ++mi)
            #pragma unroll
            for (int ni = 0; ni < 8; ++ni)
                acc[mi][ni] = __builtin_amdgcn_mfma_f32_16x16x32_bf16(
                    bfr[ni], af[mi], acc[mi][ni], 0, 0, 0);
        __syncthreads();
    }

    // ---- epilogue: 4 octants of 16 rows; LDS transpose -> contiguous streams ----
    const int g4 = (lane >> 4) << 2, c = lane & 15;
    const size_t slab = ((size_t)n * 32768 + (size_t)mt * 64) * 500;
    #pragma unroll
    for (int o = 0; o < 4; ++o) {
        __syncthreads();
        {
            const int mi = o;
            #pragma unroll
            for (int ni = 0; ni < 8; ++ni) {
                int v4 = wn * 128 + ni * 16 + g4;
                if (v4 < 500) {
                    f32x4 bias = *(const f32x4*)(bout + v4);
                    f32x4 ov;
                    ov[0] = acc[mi][ni][0] + bias[0];
                    ov[1] = acc[mi][ni][1] + bias[1];
                    ov[2] = acc[mi][ni][2] + bias[2];
                    ov[3] = acc[mi][ni][3] + bias[3];
                    *(f32x4*)(ep + c * 516 + v4) = ov;
                }
            }
        }
        __syncthreads();
        const size_t obase = slab + (size_t)o * (16 * 500);
        #pragma unroll
        for (int i = 0; i < 8; ++i) {
            int idx = i * 256 + tid;                    // f32x4 chunk id, 2000 total
            if (idx < 2000) {
                int rr = idx / 125;                     // 125 chunks per 500-f32 row
                int vi = (idx - rr * 125) * 4;
                f32x4 ov = *(const f32x4*)(ep + rr * 516 + vi);
                __builtin_nontemporal_store(ov, (f32x4*)(out + obase + (size_t)idx * 4));
            }
        }
    }
}

extern "C" void kernel_launch(void* const* d_in, const int* in_sizes, int n_in,
                              void* d_out, int out_size, void* d_ws, size_t ws_size,
                              hipStream_t stream) {
    const float* encoder_out = (const float*)d_in[0];  // [8,512,512]
    const float* decoder_out = (const float*)d_in[1];  // [8,64,512]
    const float* W_enc = (const float*)d_in[2];
    const float* b_enc = (const float*)d_in[3];
    const float* W_dec = (const float*)d_in[4];
    const float* b_dec = (const float*)d_in[5];
    const float* W_out = (const float*)d_in[6];        // [500,512]
    const float* b_out = (const float*)d_in[7];        // [500]
    float* out = (float*)d_out;                        // [8,512,64,500]

    float* enc_p = (float*)d_ws;                                   // 8 MB
    float* dec_p = enc_p + (size_t)8 * 512 * 512;                  // 1 MB
    unsigned short* wimg = (unsigned short*)(dec_p + (size_t)8 * 64 * 512);  // 512 KB

    conv_wout<<<dim3(128), 256, 0, stream>>>(W_out, wimg);
    proj_gemm<<<dim3(32, 4), 256, 0, stream>>>(encoder_out, W_enc, b_enc, enc_p);
    proj_gemm<<<dim3(4, 4), 256, 0, stream>>>(decoder_out, W_dec, b_dec, dec_p);
    joiner_main<<<dim3(4096), 256, 0, stream>>>(enc_p, dec_p, wimg, b_out, out);
}

// Round 6
// 242.408 us; speedup vs baseline: 13.9065x; 1.1134x over previous
//
#include <hip/hip_runtime.h>
#include <hip/hip_bf16.h>

// RNN-T Joiner. N=8 T=512 U=64 J=512 V=500 (padded to 512).
// ws: enc_p f32 [4096,512] (8MB) | dec_p f32 [512,512] (1MB) | wimg bf16 frag-ordered (512KB)
// joiner: BM=64 (1 t x 64 u), BN=512, BK=32, 4 waves, wave tile 64x128, mfma 32x32x16.
// B read straight from pre-formatted global image into registers (no LDS).
// LDS: A tile only (dbuf 2x4KB) in k-loop; 66KB transpose buffer in epilogue. 2 blocks/CU.

typedef __attribute__((ext_vector_type(4))) float f32x4;
typedef __attribute__((ext_vector_type(16))) float f32x16;
typedef __attribute__((ext_vector_type(8))) short s16x8;

static __device__ __forceinline__ unsigned short f2bf(float x) {
    union { float f; unsigned u; } v; v.f = x;
    return (unsigned short)((v.u + 0x7FFFu + ((v.u >> 16) & 1u)) >> 16);  // RNE
}

static __device__ __forceinline__ float fast_tanh(float x) {
    float e = __expf(2.0f * x);
    float r = __builtin_amdgcn_rcpf(e + 1.0f);
    return __builtin_fmaf(-2.0f, r, 1.0f);
}

// 64B-row swizzle for A tile: row r, 16B-slot c
static __device__ __forceinline__ unsigned swz64(int r, int c) {
    return (unsigned)(r * 64 + ((c ^ ((r >> 1) & 3)) << 4));
}

// ---------------- projection GEMM (unchanged, verified) ----------------
__global__ __launch_bounds__(256) void proj_gemm(
    const float* __restrict__ A, const float* __restrict__ W,
    const float* __restrict__ b, float* __restrict__ C)
{
    __shared__ unsigned short As[128 * 64];
    __shared__ unsigned short Bs[128 * 64];
    const int mt = blockIdx.x, jt = blockIdx.y;
    const int tid = threadIdx.x;
    const int lane = tid & 63, wid = tid >> 6;
    const int wm = wid >> 1, wn = wid & 1;

    f32x4 acc[4][4];
    const f32x4 zero = {0.f, 0.f, 0.f, 0.f};
    #pragma unroll
    for (int i = 0; i < 4; ++i)
        #pragma unroll
        for (int j = 0; j < 4; ++j) acc[i][j] = zero;

    const int c8 = (tid & 7) * 8;
    const int rbase = tid >> 3;

    for (int kt = 0; kt < 8; ++kt) {
        __syncthreads();
        #pragma unroll
        for (int p = 0; p < 4; ++p) {
            int r = p * 32 + rbase;
            int byte = (r * 128 + c8 * 2) ^ ((r & 7) << 4);
            {
                const float* s = A + (size_t)(mt * 128 + r) * 512 + kt * 64 + c8;
                f32x4 v0 = *(const f32x4*)s, v1 = *(const f32x4*)(s + 4);
                s16x8 pk;
                pk[0] = (short)f2bf(v0[0]); pk[1] = (short)f2bf(v0[1]);
                pk[2] = (short)f2bf(v0[2]); pk[3] = (short)f2bf(v0[3]);
                pk[4] = (short)f2bf(v1[0]); pk[5] = (short)f2bf(v1[1]);
                pk[6] = (short)f2bf(v1[2]); pk[7] = (short)f2bf(v1[3]);
                *(s16x8*)((char*)As + byte) = pk;
            }
            {
                const float* s = W + (size_t)(jt * 128 + r) * 512 + kt * 64 + c8;
                f32x4 v0 = *(const f32x4*)s, v1 = *(const f32x4*)(s + 4);
                s16x8 pk;
                pk[0] = (short)f2bf(v0[0]); pk[1] = (short)f2bf(v0[1]);
                pk[2] = (short)f2bf(v0[2]); pk[3] = (short)f2bf(v0[3]);
                pk[4] = (short)f2bf(v1[0]); pk[5] = (short)f2bf(v1[1]);
                pk[6] = (short)f2bf(v1[2]); pk[7] = (short)f2bf(v1[3]);
                *(s16x8*)((char*)Bs + byte) = pk;
            }
        }
        __syncthreads();
        #pragma unroll
        for (int kk = 0; kk < 2; ++kk) {
            s16x8 af[4], bfr[4];
            #pragma unroll
            for (int mi = 0; mi < 4; ++mi) {
                int row = wm * 64 + mi * 16 + (lane & 15);
                int byte = (row * 128 + kk * 64 + ((lane >> 4) * 16)) ^ ((row & 7) << 4);
                af[mi] = *(const s16x8*)((const char*)As + byte);
            }
            #pragma unroll
            for (int ni = 0; ni < 4; ++ni) {
                int row = wn * 64 + ni * 16 + (lane & 15);
                int byte = (row * 128 + kk * 64 + ((lane >> 4) * 16)) ^ ((row & 7) << 4);
                bfr[ni] = *(const s16x8*)((const char*)Bs + byte);
            }
            #pragma unroll
            for (int mi = 0; mi < 4; ++mi)
                #pragma unroll
                for (int ni = 0; ni < 4; ++ni)
                    acc[mi][ni] = __builtin_amdgcn_mfma_f32_16x16x32_bf16(
                        af[mi], bfr[ni], acc[mi][ni], 0, 0, 0);
        }
    }

    #pragma unroll
    for (int ni = 0; ni < 4; ++ni) {
        int col = jt * 128 + wn * 64 + ni * 16 + (lane & 15);
        float bias = b[col];
        #pragma unroll
        for (int mi = 0; mi < 4; ++mi) {
            int row0 = mt * 128 + wm * 64 + mi * 16 + ((lane >> 4) << 2);
            #pragma unroll
            for (int j = 0; j < 4; ++j)
                C[(size_t)(row0 + j) * 512 + col] = acc[mi][ni][j] + bias;
        }
    }
}

// ---------------- W_out -> bf16, per-lane MFMA-fragment-ordered image ----------------
// chunk tid = ((kt*16 + tile)*2 + khalf)*64 + lane -> 8 bf16 of
//   W[v = tile*32 + (lane&31)][k = kt*32 + khalf*16 + (lane>>5)*8 + j], v>=500 -> 0
__global__ __launch_bounds__(256) void conv_wout(
    const float* __restrict__ W, unsigned short* __restrict__ img)
{
    int tid = blockIdx.x * 256 + threadIdx.x;   // 32768 chunks
    int lane = tid & 63;
    int khalf = (tid >> 6) & 1;
    int tile = (tid >> 7) & 15;
    int kt = tid >> 11;
    int v = tile * 32 + (lane & 31);
    int k = kt * 32 + khalf * 16 + (lane >> 5) * 8;
    s16x8 pk = {0, 0, 0, 0, 0, 0, 0, 0};
    if (v < 500) {
        const float* s = W + (size_t)v * 512 + k;
        f32x4 a = *(const f32x4*)s, b = *(const f32x4*)(s + 4);
        pk[0] = (short)f2bf(a[0]); pk[1] = (short)f2bf(a[1]);
        pk[2] = (short)f2bf(a[2]); pk[3] = (short)f2bf(a[3]);
        pk[4] = (short)f2bf(b[0]); pk[5] = (short)f2bf(b[1]);
        pk[6] = (short)f2bf(b[2]); pk[7] = (short)f2bf(b[3]);
    }
    *(s16x8*)(img + (size_t)tid * 8) = pk;
}

// ---------------- fused tanh + vocab GEMM ----------------
__global__ __launch_bounds__(256, 2) void joiner_main(
    const float* __restrict__ enc, const float* __restrict__ dec,
    const unsigned short* __restrict__ Wimg, const float* __restrict__ bout,
    float* __restrict__ out)
{
    __shared__ __align__(16) char raw[66048];             // max(A dbuf 8KB, ep 66KB)
    unsigned short* As0 = (unsigned short*)raw;           // 4 KB [64 rows][32 k] swizzled
    unsigned short* As1 = (unsigned short*)(raw + 4096);  // 4 KB
    float* ep = (float*)raw;                              // epilogue [32][516] f32

    const int bid = blockIdx.x;                 // bid = n*512 + t
    const int tid = threadIdx.x, lane = tid & 63, wn = tid >> 6;  // 4 waves across V
    const int n = bid >> 9, t = bid & 511;

    const float* encN = enc + (size_t)n * (512 * 512);
    const float* decN = dec + (size_t)n * (64 * 512);

    f32x16 acc[2][4];
    #pragma unroll
    for (int i = 0; i < 2; ++i)
        #pragma unroll
        for (int j = 0; j < 4; ++j)
            #pragma unroll
            for (int e = 0; e < 16; ++e) acc[i][j][e] = 0.f;

    // A staging: thread stages row r = tid>>2 (u), 16B chunk c16 = tid&3
    const int r = tid >> 2;
    const int c16 = tid & 3;
    const float* erow = encN + (size_t)t * 512 + c16 * 8;
    const float* drow = decN + (size_t)r * 512 + c16 * 8;
    const unsigned abyte = swz64(r, c16);
    // B fragments: straight from global image (per-lane pre-ordered)
    const char* wbase = (const char*)Wimg + (size_t)wn * 8192 + (size_t)lane * 16;
    // a-frag read coords
    const int lr = lane & 31, kg = lane >> 5;

    f32x4 ee0, ee1, dd0, dd1;
    // ---- prologue: stage kt=0 into As0; prefetch regs for kt=1 ----
    ee0 = *(const f32x4*)erow;       ee1 = *(const f32x4*)(erow + 4);
    dd0 = *(const f32x4*)drow;       dd1 = *(const f32x4*)(drow + 4);
    {
        s16x8 p;
        p[0] = (short)f2bf(fast_tanh(ee0[0] + dd0[0]));
        p[1] = (short)f2bf(fast_tanh(ee0[1] + dd0[1]));
        p[2] = (short)f2bf(fast_tanh(ee0[2] + dd0[2]));
        p[3] = (short)f2bf(fast_tanh(ee0[3] + dd0[3]));
        p[4] = (short)f2bf(fast_tanh(ee1[0] + dd1[0]));
        p[5] = (short)f2bf(fast_tanh(ee1[1] + dd1[1]));
        p[6] = (short)f2bf(fast_tanh(ee1[2] + dd1[2]));
        p[7] = (short)f2bf(fast_tanh(ee1[3] + dd1[3]));
        *(s16x8*)((char*)As0 + abyte) = p;
        ee0 = *(const f32x4*)(erow + 32);  ee1 = *(const f32x4*)(erow + 36);
        dd0 = *(const f32x4*)(drow + 32);  dd1 = *(const f32x4*)(drow + 36);
    }
    __syncthreads();

    #pragma unroll
    for (int kt = 0; kt < 16; ++kt) {
        const char* Ac = (char*)((kt & 1) ? As1 : As0);
        char* An = (char*)((kt & 1) ? As0 : As1);

        // 1. B fragments for this kt: 8 coalesced dwordx4 from L2-resident image
        s16x8 bfr[4][2];
        {
            const char* g = wbase + (size_t)kt * 32768;
            #pragma unroll
            for (int ni = 0; ni < 4; ++ni)
                #pragma unroll
                for (int kh = 0; kh < 2; ++kh)
                    bfr[ni][kh] = *(const s16x8*)(g + ni * 2048 + kh * 1024);
        }
        // 2. A fragments from LDS
        s16x8 af[2][2];
        #pragma unroll
        for (int mi = 0; mi < 2; ++mi)
            #pragma unroll
            for (int kh = 0; kh < 2; ++kh)
                af[mi][kh] = *(const s16x8*)(Ac + swz64(mi * 32 + lr, kh * 2 + kg));
        // 3. stage next A tile (tanh) into the other buffer
        if (kt < 15) {
            s16x8 p;
            p[0] = (short)f2bf(fast_tanh(ee0[0] + dd0[0]));
            p[1] = (short)f2bf(fast_tanh(ee0[1] + dd0[1]));
            p[2] = (short)f2bf(fast_tanh(ee0[2] + dd0[2]));
            p[3] = (short)f2bf(fast_tanh(ee0[3] + dd0[3]));
            p[4] = (short)f2bf(fast_tanh(ee1[0] + dd1[0]));
            p[5] = (short)f2bf(fast_tanh(ee1[1] + dd1[1]));
            p[6] = (short)f2bf(fast_tanh(ee1[2] + dd1[2]));
            p[7] = (short)f2bf(fast_tanh(ee1[3] + dd1[3]));
            *(s16x8*)(An + abyte) = p;
        }
        // 4. register prefetch of enc/dec for kt+2's staging
        if (kt < 14) {
            const float* e_ = erow + (kt + 2) * 32;
            const float* d_ = drow + (kt + 2) * 32;
            ee0 = *(const f32x4*)e_;   ee1 = *(const f32x4*)(e_ + 4);
            dd0 = *(const f32x4*)d_;   dd1 = *(const f32x4*)(d_ + 4);
        }
        // 5. MFMA 32x32x16: D rows = v, cols = m  (k-grouping identical A/B -> cancels)
        #pragma unroll
        for (int kh = 0; kh < 2; ++kh)
            #pragma unroll
            for (int mi = 0; mi < 2; ++mi)
                #pragma unroll
                for (int ni = 0; ni < 4; ++ni)
                    acc[mi][ni] = __builtin_amdgcn_mfma_f32_32x32x16_bf16(
                        bfr[ni][kh], af[mi][kh], acc[mi][ni], 0, 0, 0);
        __syncthreads();
    }

    // ---- epilogue: 2 chunks of 32 rows; LDS transpose -> contiguous NT streams ----
    // acc[mi][ni][reg]: m = mi*32 + (lane&31),
    //                   v = wn*128 + ni*32 + (reg&3) + 8*(reg>>2) + 4*(lane>>5)
    const int hi4 = (lane >> 5) * 4;
    const size_t slab = (size_t)bid * 64 * 500;
    #pragma unroll
    for (int mi = 0; mi < 2; ++mi) {
        __syncthreads();
        #pragma unroll
        for (int ni = 0; ni < 4; ++ni) {
            int vt = wn * 128 + ni * 32;
            #pragma unroll
            for (int q = 0; q < 4; ++q) {
                int v4 = vt + q * 8 + hi4;
                if (v4 < 500) {
                    f32x4 b = *(const f32x4*)(bout + v4);
                    f32x4 o;
                    o[0] = acc[mi][ni][q * 4 + 0] + b[0];
                    o[1] = acc[mi][ni][q * 4 + 1] + b[1];
                    o[2] = acc[mi][ni][q * 4 + 2] + b[2];
                    o[3] = acc[mi][ni][q * 4 + 3] + b[3];
                    *(f32x4*)(ep + lr * 516 + v4) = o;
                }
            }
        }
        __syncthreads();
        const size_t base = slab + (size_t)mi * (32 * 500);
        #pragma unroll
        for (int i = 0; i < 16; ++i) {
            int idx = i * 256 + tid;                    // f32x4 chunk id, 4000 total
            if (idx < 4000) {
                int rr = idx / 125;
                int vi = (idx - rr * 125) * 4;
                f32x4 ov = *(const f32x4*)(ep + rr * 516 + vi);
                __builtin_nontemporal_store(ov, (f32x4*)(out + base + (size_t)idx * 4));
            }
        }
    }
}

extern "C" void kernel_launch(void* const* d_in, const int* in_sizes, int n_in,
                              void* d_out, int out_size, void* d_ws, size_t ws_size,
                              hipStream_t stream) {
    const float* encoder_out = (const float*)d_in[0];  // [8,512,512]
    const float* decoder_out = (const float*)d_in[1];  // [8,64,512]
    const float* W_enc = (const float*)d_in[2];
    const float* b_enc = (const float*)d_in[3];
    const float* W_dec = (const float*)d_in[4];
    const float* b_dec = (const float*)d_in[5];
    const float* W_out = (const float*)d_in[6];        // [500,512]
    const float* b_out = (const float*)d_in[7];        // [500]
    float* out = (float*)d_out;                        // [8,512,64,500]

    float* enc_p = (float*)d_ws;                                   // 8 MB
    float* dec_p = enc_p + (size_t)8 * 512 * 512;                  // 1 MB
    unsigned short* wimg = (unsigned short*)(dec_p + (size_t)8 * 64 * 512);  // 512 KB

    conv_wout<<<dim3(128), 256, 0, stream>>>(W_out, wimg);
    proj_gemm<<<dim3(32, 4), 256, 0, stream>>>(encoder_out, W_enc, b_enc, enc_p);
    proj_gemm<<<dim3(4, 4), 256, 0, stream>>>(decoder_out, W_dec, b_dec, dec_p);
    joiner_main<<<dim3(4096), 256, 0, stream>>>(enc_p, dec_p, wimg, b_out, out);
}

// Round 7
// 239.073 us; speedup vs baseline: 14.1005x; 1.0139x over previous
//
#include <hip/hip_runtime.h>
#include <hip/hip_bf16.h>

// RNN-T Joiner. N=8 T=512 U=64 J=512 V=500 (padded 512).
// ws: enc_p f32 [4096,512] | dec_p f32 [512,512] | wimg bf16 frag-ordered (512KB)
// prep: one kernel = conv_wout (128 blk) + enc proj (128 blk) + dec proj (16 blk)
// joiner: 512 thr / 8 waves, BM=64, BN=512, BK=32, wave tile 64m x 64v, mfma 32x32x16.
//   acc 64 VGPR -> launch_bounds(512,4) => 16 waves/CU (2 blocks), LDS 41KB/block.
//   B from pre-formatted global image straight to regs; A tanh-staged in 8KB LDS dbuf.
//   Epilogue: 4 rounds x 16 rows via 33KB LDS transpose -> linear 32KB NT streams.

typedef __attribute__((ext_vector_type(4))) float f32x4;
typedef __attribute__((ext_vector_type(16))) float f32x16;
typedef __attribute__((ext_vector_type(4))) short s16x4;
typedef __attribute__((ext_vector_type(8))) short s16x8;

static __device__ __forceinline__ unsigned short f2bf(float x) {
    union { float f; unsigned u; } v; v.f = x;
    return (unsigned short)((v.u + 0x7FFFu + ((v.u >> 16) & 1u)) >> 16);  // RNE
}

static __device__ __forceinline__ float fast_tanh(float x) {
    float e = __expf(2.0f * x);
    float r = __builtin_amdgcn_rcpf(e + 1.0f);
    return __builtin_fmaf(-2.0f, r, 1.0f);
}

// 64B-row swizzle: row r, 16B-slot c; byte = r*64 + ((c ^ ((r>>1)&3)) << 4)
static __device__ __forceinline__ unsigned swz64(int r, int c) {
    return (unsigned)(r * 64 + ((c ^ ((r >> 1) & 3)) << 4));
}

// ---------------- projection GEMM body (verified structure) ----------------
static __device__ void proj_body(
    const float* __restrict__ A, const float* __restrict__ W,
    const float* __restrict__ b, float* __restrict__ C,
    int mt, int jt, unsigned short* As, unsigned short* Bs)
{
    const int tid = threadIdx.x;
    const int lane = tid & 63, wid = tid >> 6;
    const int wm = wid >> 1, wn = wid & 1;

    f32x4 acc[4][4];
    const f32x4 zero = {0.f, 0.f, 0.f, 0.f};
    #pragma unroll
    for (int i = 0; i < 4; ++i)
        #pragma unroll
        for (int j = 0; j < 4; ++j) acc[i][j] = zero;

    const int c8 = (tid & 7) * 8;
    const int rbase = tid >> 3;

    for (int kt = 0; kt < 8; ++kt) {
        __syncthreads();
        #pragma unroll
        for (int p = 0; p < 4; ++p) {
            int r = p * 32 + rbase;
            int byte = (r * 128 + c8 * 2) ^ ((r & 7) << 4);
            {
                const float* s = A + (size_t)(mt * 128 + r) * 512 + kt * 64 + c8;
                f32x4 v0 = *(const f32x4*)s, v1 = *(const f32x4*)(s + 4);
                s16x8 pk;
                pk[0] = (short)f2bf(v0[0]); pk[1] = (short)f2bf(v0[1]);
                pk[2] = (short)f2bf(v0[2]); pk[3] = (short)f2bf(v0[3]);
                pk[4] = (short)f2bf(v1[0]); pk[5] = (short)f2bf(v1[1]);
                pk[6] = (short)f2bf(v1[2]); pk[7] = (short)f2bf(v1[3]);
                *(s16x8*)((char*)As + byte) = pk;
            }
            {
                const float* s = W + (size_t)(jt * 128 + r) * 512 + kt * 64 + c8;
                f32x4 v0 = *(const f32x4*)s, v1 = *(const f32x4*)(s + 4);
                s16x8 pk;
                pk[0] = (short)f2bf(v0[0]); pk[1] = (short)f2bf(v0[1]);
                pk[2] = (short)f2bf(v0[2]); pk[3] = (short)f2bf(v0[3]);
                pk[4] = (short)f2bf(v1[0]); pk[5] = (short)f2bf(v1[1]);
                pk[6] = (short)f2bf(v1[2]); pk[7] = (short)f2bf(v1[3]);
                *(s16x8*)((char*)Bs + byte) = pk;
            }
        }
        __syncthreads();
        #pragma unroll
        for (int kk = 0; kk < 2; ++kk) {
            s16x8 af[4], bfr[4];
            #pragma unroll
            for (int mi = 0; mi < 4; ++mi) {
                int row = wm * 64 + mi * 16 + (lane & 15);
                int byte = (row * 128 + kk * 64 + ((lane >> 4) * 16)) ^ ((row & 7) << 4);
                af[mi] = *(const s16x8*)((const char*)As + byte);
            }
            #pragma unroll
            for (int ni = 0; ni < 4; ++ni) {
                int row = wn * 64 + ni * 16 + (lane & 15);
                int byte = (row * 128 + kk * 64 + ((lane >> 4) * 16)) ^ ((row & 7) << 4);
                bfr[ni] = *(const s16x8*)((const char*)Bs + byte);
            }
            #pragma unroll
            for (int mi = 0; mi < 4; ++mi)
                #pragma unroll
                for (int ni = 0; ni < 4; ++ni)
                    acc[mi][ni] = __builtin_amdgcn_mfma_f32_16x16x32_bf16(
                        af[mi], bfr[ni], acc[mi][ni], 0, 0, 0);
        }
    }

    #pragma unroll
    for (int ni = 0; ni < 4; ++ni) {
        int col = jt * 128 + wn * 64 + ni * 16 + (lane & 15);
        float bias = b[col];
        #pragma unroll
        for (int mi = 0; mi < 4; ++mi) {
            int row0 = mt * 128 + wm * 64 + mi * 16 + ((lane >> 4) << 2);
            #pragma unroll
            for (int j = 0; j < 4; ++j)
                C[(size_t)(row0 + j) * 512 + col] = acc[mi][ni][j] + bias;
        }
    }
}

// ---------------- fused prep: conv_wout | enc proj | dec proj ----------------
__global__ __launch_bounds__(256) void prep(
    const float* __restrict__ Wout, unsigned short* __restrict__ img,
    const float* __restrict__ encoder_out, const float* __restrict__ W_enc,
    const float* __restrict__ b_enc, float* __restrict__ enc_p,
    const float* __restrict__ decoder_out, const float* __restrict__ W_dec,
    const float* __restrict__ b_dec, float* __restrict__ dec_p)
{
    __shared__ unsigned short As[128 * 64];
    __shared__ unsigned short Bs[128 * 64];
    const int b = blockIdx.x;
    if (b < 128) {
        // W_out -> bf16 per-lane MFMA-fragment-ordered image:
        // chunk tid = ((kt*16+tile)*2+khalf)*64+lane -> 8 bf16 of
        //   W[v=tile*32+(lane&31)][k=kt*32+khalf*16+(lane>>5)*8 + j], v>=500 -> 0
        int tid = b * 256 + threadIdx.x;
        int lane = tid & 63;
        int khalf = (tid >> 6) & 1;
        int tile = (tid >> 7) & 15;
        int kt = tid >> 11;
        int v = tile * 32 + (lane & 31);
        int k = kt * 32 + khalf * 16 + (lane >> 5) * 8;
        s16x8 pk = {0, 0, 0, 0, 0, 0, 0, 0};
        if (v < 500) {
            const float* s = Wout + (size_t)v * 512 + k;
            f32x4 a = *(const f32x4*)s, c = *(const f32x4*)(s + 4);
            pk[0] = (short)f2bf(a[0]); pk[1] = (short)f2bf(a[1]);
            pk[2] = (short)f2bf(a[2]); pk[3] = (short)f2bf(a[3]);
            pk[4] = (short)f2bf(c[0]); pk[5] = (short)f2bf(c[1]);
            pk[6] = (short)f2bf(c[2]); pk[7] = (short)f2bf(c[3]);
        }
        *(s16x8*)(img + (size_t)tid * 8) = pk;
    } else if (b < 256) {
        int q = b - 128;                       // enc proj: M=4096
        proj_body(encoder_out, W_enc, b_enc, enc_p, q & 31, q >> 5, As, Bs);
    } else {
        int q = b - 256;                       // dec proj: M=512
        proj_body(decoder_out, W_dec, b_dec, dec_p, q & 3, q >> 2, As, Bs);
    }
}

// ---------------- fused tanh + vocab GEMM ----------------
__global__ __launch_bounds__(512, 4) void joiner_main(
    const float* __restrict__ enc, const float* __restrict__ dec,
    const unsigned short* __restrict__ Wimg, const float* __restrict__ bout,
    float* __restrict__ out)
{
    __shared__ __align__(16) char raw[8192 + 33024];      // A dbuf 8KB | ep [16][516] f32
    unsigned short* As0 = (unsigned short*)raw;           // 4 KB [64 r][32 k] swizzled
    unsigned short* As1 = (unsigned short*)(raw + 4096);
    float* ep = (float*)(raw + 8192);

    const int bid = blockIdx.x;                 // bid = n*512 + t
    const int tid = threadIdx.x, lane = tid & 63, wn = tid >> 6;  // 8 waves across V
    const int n = bid >> 9, t = bid & 511;

    f32x16 acc[2][2];
    #pragma unroll
    for (int i = 0; i < 2; ++i)
        #pragma unroll
        for (int j = 0; j < 2; ++j)
            #pragma unroll
            for (int e = 0; e < 16; ++e) acc[i][j][e] = 0.f;

    // A staging: thread -> row r = tid>>3 (u 0..63), 8B chunk q8 = tid&7 (k = q8*4..+3)
    const int r = tid >> 3;
    const int q8 = tid & 7;
    const float* erow = enc + ((size_t)n * 512 + t) * 512 + q8 * 4;
    const float* drow = dec + ((size_t)n * 64 + r) * 512 + q8 * 4;
    const unsigned abyte = swz64(r, q8 >> 1) + (q8 & 1) * 8;
    // B fragments: global image, per-lane pre-ordered. wave wn owns v-tiles wn*2+{0,1}
    const char* wbase = (const char*)Wimg + (size_t)wn * 4096 + (size_t)lane * 16;
    const int lr = lane & 31, kg = lane >> 5;

    // ---- prologue: stage kt=0 into As0 ----
    {
        f32x4 e0 = *(const f32x4*)erow;
        f32x4 d0 = *(const f32x4*)drow;
        s16x4 p;
        p[0] = (short)f2bf(fast_tanh(e0[0] + d0[0]));
        p[1] = (short)f2bf(fast_tanh(e0[1] + d0[1]));
        p[2] = (short)f2bf(fast_tanh(e0[2] + d0[2]));
        p[3] = (short)f2bf(fast_tanh(e0[3] + d0[3]));
        *(s16x4*)((char*)As0 + abyte) = p;
    }
    __syncthreads();

    #pragma unroll
    for (int kt = 0; kt < 16; ++kt) {
        const char* Ac = (char*)((kt & 1) ? As1 : As0);
        char* An = (char*)((kt & 1) ? As0 : As1);

        // 1. B fragments: 4 coalesced dwordx4 from L2-resident image
        s16x8 bfr[2][2];
        {
            const char* g = wbase + (size_t)kt * 32768;
            #pragma unroll
            for (int ni = 0; ni < 2; ++ni)
                #pragma unroll
                for (int kh = 0; kh < 2; ++kh)
                    bfr[ni][kh] = *(const s16x8*)(g + ni * 2048 + kh * 1024);
        }
        // 2. A fragments from LDS
        s16x8 af[2][2];
        #pragma unroll
        for (int mi = 0; mi < 2; ++mi)
            #pragma unroll
            for (int kh = 0; kh < 2; ++kh)
                af[mi][kh] = *(const s16x8*)(Ac + swz64(mi * 32 + lr, kh * 2 + kg));
        // 3. stage next A tile
        if (kt < 15) {
            const float* e_ = erow + (kt + 1) * 32;
            const float* d_ = drow + (kt + 1) * 32;
            f32x4 e0 = *(const f32x4*)e_;
            f32x4 d0 = *(const f32x4*)d_;
            s16x4 p;
            p[0] = (short)f2bf(fast_tanh(e0[0] + d0[0]));
            p[1] = (short)f2bf(fast_tanh(e0[1] + d0[1]));
            p[2] = (short)f2bf(fast_tanh(e0[2] + d0[2]));
            p[3] = (short)f2bf(fast_tanh(e0[3] + d0[3]));
            *(s16x4*)(An + abyte) = p;
        }
        // 4. MFMA 32x32x16 swapped: D cols = m (lane&31), rows = v
        #pragma unroll
        for (int kh = 0; kh < 2; ++kh)
            #pragma unroll
            for (int mi = 0; mi < 2; ++mi)
                #pragma unroll
                for (int ni = 0; ni < 2; ++ni)
                    acc[mi][ni] = __builtin_amdgcn_mfma_f32_32x32x16_bf16(
                        bfr[ni][kh], af[mi][kh], acc[mi][ni], 0, 0, 0);
        __syncthreads();
    }

    // ---- epilogue: 4 rounds of 16 rows; LDS transpose -> linear NT streams ----
    // acc[mi][ni][reg]: m = mi*32 + (lane&31),
    //                   v = wn*64 + ni*32 + (reg&3) + 8*(reg>>2) + 4*(lane>>5)
    const int hi4 = (lane >> 5) * 4;
    const int lr16 = lane & 15;
    #pragma unroll
    for (int o = 0; o < 4; ++o) {
        __syncthreads();   // prev round's ep reads done (drains stores too; inter-block overlap)
        if (((lane >> 4) & 1) == (o & 1)) {
            const int mi = o >> 1;
            #pragma unroll
            for (int ni = 0; ni < 2; ++ni) {
                #pragma unroll
                for (int q = 0; q < 4; ++q) {
                    int v4 = wn * 64 + ni * 32 + q * 8 + hi4;
                    f32x4 b = *(const f32x4*)(bout + v4);   // bout padded-read ok (<512)
                    f32x4 ov;
                    ov[0] = acc[mi][ni == 0 ? 0 : 1][q * 4 + 0] + b[0];
                    ov[1] = acc[mi][ni == 0 ? 0 : 1][q * 4 + 1] + b[1];
                    ov[2] = acc[mi][ni == 0 ? 0 : 1][q * 4 + 2] + b[2];
                    ov[3] = acc[mi][ni == 0 ? 0 : 1][q * 4 + 3] + b[3];
                    *(f32x4*)(ep + lr16 * 516 + v4) = ov;
                }
            }
        }
        __syncthreads();
        const size_t obase = ((size_t)bid * 64 + o * 16) * 500;
        #pragma unroll
        for (int i = 0; i < 4; ++i) {
            int idx = i * 512 + tid;                    // f32x4 chunk, 2000 total
            if (idx < 2000) {
                int rr = idx / 125;
                int vi = (idx - rr * 125) * 4;
                f32x4 ov = *(const f32x4*)(ep + rr * 516 + vi);
                __builtin_nontemporal_store(ov, (f32x4*)(out + obase + (size_t)idx * 4));
            }
        }
    }
}

extern "C" void kernel_launch(void* const* d_in, const int* in_sizes, int n_in,
                              void* d_out, int out_size, void* d_ws, size_t ws_size,
                              hipStream_t stream) {
    const float* encoder_out = (const float*)d_in[0];  // [8,512,512]
    const float* decoder_out = (const float*)d_in[1];  // [8,64,512]
    const float* W_enc = (const float*)d_in[2];
    const float* b_enc = (const float*)d_in[3];
    const float* W_dec = (const float*)d_in[4];
    const float* b_dec = (const float*)d_in[5];
    const float* W_out = (const float*)d_in[6];        // [500,512]
    const float* b_out = (const float*)d_in[7];        // [500]
    float* out = (float*)d_out;                        // [8,512,64,500]

    float* enc_p = (float*)d_ws;                                   // 8 MB
    float* dec_p = enc_p + (size_t)8 * 512 * 512;                  // 1 MB
    unsigned short* wimg = (unsigned short*)(dec_p + (size_t)8 * 64 * 512);  // 512 KB
    // note: b_out has 500 elems; epilogue reads f32x4 up to v=511 -> pad via ws copy
    // (avoid OOB: copy b_out into a 512-padded ws slot)
    // [handled below by a tiny pad region]
    float* bpad = (float*)(wimg + (size_t)8 * 65536 / 2 * 2);      // after 512KB image

    prep<<<dim3(272), 256, 0, stream>>>(W_out, wimg,
                                        encoder_out, W_enc, b_enc, enc_p,
                                        decoder_out, W_dec, b_dec, dec_p);
    // pad b_out to 512 floats in ws (async d2d + small memset)
    hipMemsetAsync(bpad, 0, 512 * sizeof(float), stream);
    hipMemcpyAsync(bpad, b_out, 500 * sizeof(float), hipMemcpyDeviceToDevice, stream);
    joiner_main<<<dim3(4096), 512, 0, stream>>>(enc_p, dec_p, wimg, bpad, out);
}

// Round 8
// 225.632 us; speedup vs baseline: 14.9405x; 1.0596x over previous
//
#include <hip/hip_runtime.h>
#include <hip/hip_bf16.h>

// RNN-T Joiner. N=8 T=512 U=64 J=512 V=500 (padded 512).
// ws: enc_p bf16 [4096,512] (4MB) | dec_p bf16 [512,512] (512KB) | wimg bf16 frag-ordered
//     (512KB) | bpad f32[512]
// prep (273 blocks): conv_wout (128) | enc proj (128) | dec proj (16) | bpad (1)
// joiner: 512 thr / 8 waves, BM=64, BN=512, BK=32, wave tile 64m x 64v, mfma 32x32x16.
//   B from frag-ordered global image straight to regs; A tanh-staged in 8KB LDS dbuf.
//   bf16 A-loads (half VMEM). Epilogue: 2 rounds x 32 rows via 66KB LDS (aliased) ->
//   linear NT streams. launch_bounds(512,4) -> <=128 VGPR -> 2 blocks/CU.

typedef __attribute__((ext_vector_type(4))) float f32x4;
typedef __attribute__((ext_vector_type(16))) float f32x16;
typedef __attribute__((ext_vector_type(4))) short s16x4;
typedef __attribute__((ext_vector_type(8))) short s16x8;
typedef __attribute__((ext_vector_type(4))) unsigned short u16x4;

static __device__ __forceinline__ unsigned short f2bf(float x) {
    union { float f; unsigned u; } v; v.f = x;
    return (unsigned short)((v.u + 0x7FFFu + ((v.u >> 16) & 1u)) >> 16);  // RNE
}

static __device__ __forceinline__ float bf2f(unsigned short u) {
    union { unsigned u; float f; } v; v.u = ((unsigned)u) << 16;
    return v.f;
}

static __device__ __forceinline__ float fast_tanh(float x) {
    float e = __expf(2.0f * x);
    float r = __builtin_amdgcn_rcpf(e + 1.0f);
    return __builtin_fmaf(-2.0f, r, 1.0f);
}

// 64B-row swizzle: row r, 16B-slot c; byte = r*64 + ((c ^ ((r>>1)&3)) << 4)
static __device__ __forceinline__ unsigned swz64(int r, int c) {
    return (unsigned)(r * 64 + ((c ^ ((r >> 1) & 3)) << 4));
}

// ---------------- projection GEMM body (verified structure; bf16 output) ----------------
static __device__ void proj_body(
    const float* __restrict__ A, const float* __restrict__ W,
    const float* __restrict__ b, unsigned short* __restrict__ C,
    int mt, int jt, unsigned short* As, unsigned short* Bs)
{
    const int tid = threadIdx.x;
    const int lane = tid & 63, wid = tid >> 6;
    const int wm = wid >> 1, wn = wid & 1;

    f32x4 acc[4][4];
    const f32x4 zero = {0.f, 0.f, 0.f, 0.f};
    #pragma unroll
    for (int i = 0; i < 4; ++i)
        #pragma unroll
        for (int j = 0; j < 4; ++j) acc[i][j] = zero;

    const int c8 = (tid & 7) * 8;
    const int rbase = tid >> 3;

    for (int kt = 0; kt < 8; ++kt) {
        __syncthreads();
        #pragma unroll
        for (int p = 0; p < 4; ++p) {
            int r = p * 32 + rbase;
            int byte = (r * 128 + c8 * 2) ^ ((r & 7) << 4);
            {
                const float* s = A + (size_t)(mt * 128 + r) * 512 + kt * 64 + c8;
                f32x4 v0 = *(const f32x4*)s, v1 = *(const f32x4*)(s + 4);
                s16x8 pk;
                pk[0] = (short)f2bf(v0[0]); pk[1] = (short)f2bf(v0[1]);
                pk[2] = (short)f2bf(v0[2]); pk[3] = (short)f2bf(v0[3]);
                pk[4] = (short)f2bf(v1[0]); pk[5] = (short)f2bf(v1[1]);
                pk[6] = (short)f2bf(v1[2]); pk[7] = (short)f2bf(v1[3]);
                *(s16x8*)((char*)As + byte) = pk;
            }
            {
                const float* s = W + (size_t)(jt * 128 + r) * 512 + kt * 64 + c8;
                f32x4 v0 = *(const f32x4*)s, v1 = *(const f32x4*)(s + 4);
                s16x8 pk;
                pk[0] = (short)f2bf(v0[0]); pk[1] = (short)f2bf(v0[1]);
                pk[2] = (short)f2bf(v0[2]); pk[3] = (short)f2bf(v0[3]);
                pk[4] = (short)f2bf(v1[0]); pk[5] = (short)f2bf(v1[1]);
                pk[6] = (short)f2bf(v1[2]); pk[7] = (short)f2bf(v1[3]);
                *(s16x8*)((char*)Bs + byte) = pk;
            }
        }
        __syncthreads();
        #pragma unroll
        for (int kk = 0; kk < 2; ++kk) {
            s16x8 af[4], bfr[4];
            #pragma unroll
            for (int mi = 0; mi < 4; ++mi) {
                int row = wm * 64 + mi * 16 + (lane & 15);
                int byte = (row * 128 + kk * 64 + ((lane >> 4) * 16)) ^ ((row & 7) << 4);
                af[mi] = *(const s16x8*)((const char*)As + byte);
            }
            #pragma unroll
            for (int ni = 0; ni < 4; ++ni) {
                int row = wn * 64 + ni * 16 + (lane & 15);
                int byte = (row * 128 + kk * 64 + ((lane >> 4) * 16)) ^ ((row & 7) << 4);
                bfr[ni] = *(const s16x8*)((const char*)Bs + byte);
            }
            #pragma unroll
            for (int mi = 0; mi < 4; ++mi)
                #pragma unroll
                for (int ni = 0; ni < 4; ++ni)
                    acc[mi][ni] = __builtin_amdgcn_mfma_f32_16x16x32_bf16(
                        af[mi], bfr[ni], acc[mi][ni], 0, 0, 0);
        }
    }

    #pragma unroll
    for (int ni = 0; ni < 4; ++ni) {
        int col = jt * 128 + wn * 64 + ni * 16 + (lane & 15);
        float bias = b[col];
        #pragma unroll
        for (int mi = 0; mi < 4; ++mi) {
            int row0 = mt * 128 + wm * 64 + mi * 16 + ((lane >> 4) << 2);
            #pragma unroll
            for (int j = 0; j < 4; ++j)
                C[(size_t)(row0 + j) * 512 + col] = f2bf(acc[mi][ni][j] + bias);
        }
    }
}

// ---------------- fused prep: conv_wout | enc proj | dec proj | bpad ----------------
__global__ __launch_bounds__(256) void prep(
    const float* __restrict__ Wout, unsigned short* __restrict__ img,
    const float* __restrict__ encoder_out, const float* __restrict__ W_enc,
    const float* __restrict__ b_enc, unsigned short* __restrict__ enc_p,
    const float* __restrict__ decoder_out, const float* __restrict__ W_dec,
    const float* __restrict__ b_dec, unsigned short* __restrict__ dec_p,
    const float* __restrict__ b_out, float* __restrict__ bpad)
{
    __shared__ unsigned short As[128 * 64];
    __shared__ unsigned short Bs[128 * 64];
    const int b = blockIdx.x;
    if (b < 128) {
        // W_out -> bf16 per-lane MFMA-fragment-ordered image (verified R6/R7 layout):
        // chunk tid = ((kt*16+tile)*2+khalf)*64+lane -> 8 bf16 of
        //   W[v=tile*32+(lane&31)][k=kt*32+khalf*16+(lane>>5)*8 + j], v>=500 -> 0
        int tid = b * 256 + threadIdx.x;
        int lane = tid & 63;
        int khalf = (tid >> 6) & 1;
        int tile = (tid >> 7) & 15;
        int kt = tid >> 11;
        int v = tile * 32 + (lane & 31);
        int k = kt * 32 + khalf * 16 + (lane >> 5) * 8;
        s16x8 pk = {0, 0, 0, 0, 0, 0, 0, 0};
        if (v < 500) {
            const float* s = Wout + (size_t)v * 512 + k;
            f32x4 a = *(const f32x4*)s, c = *(const f32x4*)(s + 4);
            pk[0] = (short)f2bf(a[0]); pk[1] = (short)f2bf(a[1]);
            pk[2] = (short)f2bf(a[2]); pk[3] = (short)f2bf(a[3]);
            pk[4] = (short)f2bf(c[0]); pk[5] = (short)f2bf(c[1]);
            pk[6] = (short)f2bf(c[2]); pk[7] = (short)f2bf(c[3]);
        }
        *(s16x8*)(img + (size_t)tid * 8) = pk;
    } else if (b < 256) {
        int q = b - 128;                       // enc proj: M=4096
        proj_body(encoder_out, W_enc, b_enc, enc_p, q & 31, q >> 5, As, Bs);
    } else if (b < 272) {
        int q = b - 256;                       // dec proj: M=512
        proj_body(decoder_out, W_dec, b_dec, dec_p, q & 3, q >> 2, As, Bs);
    } else {
        int i = threadIdx.x;                   // bpad: 512-padded bias
        bpad[i] = (i < 500) ? b_out[i] : 0.f;
        bpad[i + 256] = (i + 256 < 500) ? b_out[i + 256] : 0.f;
    }
}

// ---------------- fused tanh + vocab GEMM ----------------
__global__ __launch_bounds__(512, 4) void joiner_main(
    const unsigned short* __restrict__ enc, const unsigned short* __restrict__ dec,
    const unsigned short* __restrict__ Wimg, const float* __restrict__ bout,
    float* __restrict__ out)
{
    __shared__ __align__(16) char raw[66048];             // ep [32][516] f32, aliases A dbuf
    unsigned short* As0 = (unsigned short*)raw;           // 4 KB [64 r][32 k] swizzled
    unsigned short* As1 = (unsigned short*)(raw + 4096);
    float* ep = (float*)raw;

    const int bid = blockIdx.x;                 // bid = n*512 + t
    const int tid = threadIdx.x, lane = tid & 63, wn = tid >> 6;  // 8 waves across V
    const int n = bid >> 9, t = bid & 511;

    f32x16 acc[2][2];
    #pragma unroll
    for (int i = 0; i < 2; ++i)
        #pragma unroll
        for (int j = 0; j < 2; ++j)
            #pragma unroll
            for (int e = 0; e < 16; ++e) acc[i][j][e] = 0.f;

    // A staging: thread -> row r = tid>>3 (u 0..63), 8B chunk q = tid&7 (k = q*4..+3)
    const int r = tid >> 3;
    const int q = tid & 7;
    const unsigned short* erow = enc + ((size_t)n * 512 + t) * 512 + q * 4;
    const unsigned short* drow = dec + ((size_t)n * 64 + r) * 512 + q * 4;
    const unsigned abyte = swz64(r, q >> 1) + (q & 1) * 8;
    // B fragments: global image, per-lane pre-ordered. wave wn owns v-tiles wn*2+{0,1}
    const char* wbase = (const char*)Wimg + (size_t)wn * 4096 + (size_t)lane * 16;
    const int lr = lane & 31, kg = lane >> 5;

    // ---- prologue: stage kt=0 into As0 ----
    {
        u16x4 e = *(const u16x4*)erow;
        u16x4 d = *(const u16x4*)drow;
        s16x4 p;
        p[0] = (short)f2bf(fast_tanh(bf2f(e[0]) + bf2f(d[0])));
        p[1] = (short)f2bf(fast_tanh(bf2f(e[1]) + bf2f(d[1])));
        p[2] = (short)f2bf(fast_tanh(bf2f(e[2]) + bf2f(d[2])));
        p[3] = (short)f2bf(fast_tanh(bf2f(e[3]) + bf2f(d[3])));
        *(s16x4*)((char*)As0 + abyte) = p;
    }
    __syncthreads();

    #pragma unroll
    for (int kt = 0; kt < 16; ++kt) {
        const char* Ac = (char*)((kt & 1) ? As1 : As0);
        char* An = (char*)((kt & 1) ? As0 : As1);
        const char* g = wbase + (size_t)kt * 32768;

        // stage next A tile (issue loads early; tanh overlaps MFMA on VALU pipe)
        if (kt < 15) {
            u16x4 e = *(const u16x4*)(erow + (kt + 1) * 32);
            u16x4 d = *(const u16x4*)(drow + (kt + 1) * 32);
            s16x4 p;
            p[0] = (short)f2bf(fast_tanh(bf2f(e[0]) + bf2f(d[0])));
            p[1] = (short)f2bf(fast_tanh(bf2f(e[1]) + bf2f(d[1])));
            p[2] = (short)f2bf(fast_tanh(bf2f(e[2]) + bf2f(d[2])));
            p[3] = (short)f2bf(fast_tanh(bf2f(e[3]) + bf2f(d[3])));
            *(s16x4*)(An + abyte) = p;
        }
        // per-kh fragment loads + MFMA (keeps live regs <=128 for 2 blocks/CU)
        #pragma unroll
        for (int kh = 0; kh < 2; ++kh) {
            s16x8 b0 = *(const s16x8*)(g + 0 * 2048 + kh * 1024);
            s16x8 b1 = *(const s16x8*)(g + 1 * 2048 + kh * 1024);
            s16x8 a0 = *(const s16x8*)(Ac + swz64(lr, kh * 2 + kg));
            s16x8 a1 = *(const s16x8*)(Ac + swz64(32 + lr, kh * 2 + kg));
            acc[0][0] = __builtin_amdgcn_mfma_f32_32x32x16_bf16(b0, a0, acc[0][0], 0, 0, 0);
            acc[0][1] = __builtin_amdgcn_mfma_f32_32x32x16_bf16(b1, a0, acc[0][1], 0, 0, 0);
            acc[1][0] = __builtin_amdgcn_mfma_f32_32x32x16_bf16(b0, a1, acc[1][0], 0, 0, 0);
            acc[1][1] = __builtin_amdgcn_mfma_f32_32x32x16_bf16(b1, a1, acc[1][1], 0, 0, 0);
        }
        __syncthreads();
    }

    // ---- epilogue: 2 rounds of 32 rows; LDS transpose -> linear NT streams ----
    // acc[mi][ni][reg]: m = mi*32 + (lane&31),
    //                   v = wn*64 + ni*32 + (reg&3) + 8*(reg>>2) + 4*(lane>>5)
    const int hi4 = (lane >> 5) * 4;
    #pragma unroll
    for (int o = 0; o < 2; ++o) {
        // k-loop's final barrier covers round 0; round 1 needs round 0's reads done
        if (o) __syncthreads();
        {
            const int mi = o;
            #pragma unroll
            for (int ni = 0; ni < 2; ++ni) {
                #pragma unroll
                for (int qq = 0; qq < 4; ++qq) {
                    int v4 = wn * 64 + ni * 32 + qq * 8 + hi4;
                    if (v4 < 500) {
                        f32x4 b = *(const f32x4*)(bout + v4);   // bout 512-padded
                        f32x4 ov;
                        ov[0] = acc[mi][ni][qq * 4 + 0] + b[0];
                        ov[1] = acc[mi][ni][qq * 4 + 1] + b[1];
                        ov[2] = acc[mi][ni][qq * 4 + 2] + b[2];
                        ov[3] = acc[mi][ni][qq * 4 + 3] + b[3];
                        *(f32x4*)(ep + lr * 516 + v4) = ov;
                    }
                }
            }
        }
        __syncthreads();
        const size_t obase = ((size_t)bid * 64 + o * 32) * 500;
        #pragma unroll
        for (int i = 0; i < 8; ++i) {
            int idx = i * 512 + tid;                    // f32x4 chunk, 4000 total
            if (idx < 4000) {
                int rr = idx / 125;
                int vi = (idx - rr * 125) * 4;
                f32x4 ov = *(const f32x4*)(ep + rr * 516 + vi);
                __builtin_nontemporal_store(ov, (f32x4*)(out + obase + (size_t)idx * 4));
            }
        }
    }
}

extern "C" void kernel_launch(void* const* d_in, const int* in_sizes, int n_in,
                              void* d_out, int out_size, void* d_ws, size_t ws_size,
                              hipStream_t stream) {
    const float* encoder_out = (const float*)d_in[0];  // [8,512,512]
    const float* decoder_out = (const float*)d_in[1];  // [8,64,512]
    const float* W_enc = (const float*)d_in[2];
    const float* b_enc = (const float*)d_in[3];
    const float* W_dec = (const float*)d_in[4];
    const float* b_dec = (const float*)d_in[5];
    const float* W_out = (const float*)d_in[6];        // [500,512]
    const float* b_out = (const float*)d_in[7];        // [500]
    float* out = (float*)d_out;                        // [8,512,64,500]

    unsigned short* enc_p = (unsigned short*)d_ws;              // 4 MB bf16
    unsigned short* dec_p = enc_p + (size_t)4096 * 512;         // 512 KB bf16
    unsigned short* wimg  = dec_p + (size_t)512 * 512;          // 512 KB bf16
    float* bpad = (float*)(wimg + 262144);                      // 2 KB f32

    prep<<<dim3(273), 256, 0, stream>>>(W_out, wimg,
                                        encoder_out, W_enc, b_enc, enc_p,
                                        decoder_out, W_dec, b_dec, dec_p,
                                        b_out, bpad);
    joiner_main<<<dim3(4096), 512, 0, stream>>>(enc_p, dec_p, wimg, bpad, out);
}